// Round 4
// baseline (2490.839 us; speedup 1.0000x reference)
//
#include <hip/hip_runtime.h>

#define NBLK 256
#define ROWS 18

__device__ __forceinline__ float dot4(float4 a, float4 b){
  return fmaf(a.x,b.x, fmaf(a.y,b.y, fmaf(a.z,b.z, a.w*b.w)));
}
__device__ __forceinline__ void fma4(float& acc, float4 w, float4 a){
  acc = fmaf(w.x,a.x, fmaf(w.y,a.y, fmaf(w.z,a.z, fmaf(w.w,a.w, acc))));
}
__device__ __forceinline__ float wred(float v){
  #pragma unroll
  for (int m = 32; m >= 1; m >>= 1) v += __shfl_xor(v, m);
  return v;
}

// Device-wide barrier. __syncthreads drains vmcnt for all waves, so a single
// per-block threadfence (wbl2/inv) makes the block's stores visible device-wide.
__device__ __forceinline__ void gbar(unsigned* p){
  __syncthreads();
  if (threadIdx.x == 0) {
    __threadfence();   // release: write back this XCD's dirty L2
    __hip_atomic_fetch_add(p, 1u, __ATOMIC_RELAXED, __HIP_MEMORY_SCOPE_AGENT);
    while (__hip_atomic_load(p, __ATOMIC_RELAXED, __HIP_MEMORY_SCOPE_AGENT) < NBLK)
      __builtin_amdgcn_s_sleep(2);
    __threadfence();   // acquire: invalidate stale L1/L2 lines
  }
  __syncthreads();
}

__global__ __launch_bounds__(512, 2)
void vox_persist(const int* __restrict__ step, const float* __restrict__ random_,
                 const float* __restrict__ dit_h, const float* __restrict__ feat,
                 const float* __restrict__ cfg, const float* __restrict__ cfgm,
                 const float* __restrict__ t_emb, const float* __restrict__ dt,
                 const float* __restrict__ in_w, const float* __restrict__ in_b,
                 const float* __restrict__ qkv_w, const float* __restrict__ qkv_b,
                 const float* __restrict__ o_w, const float* __restrict__ gu_w,
                 const float* __restrict__ dn_w, const float* __restrict__ op_w,
                 const float* __restrict__ op_b,
                 unsigned* __restrict__ bars,
                 float* __restrict__ hs, float* __restrict__ qkvb,
                 float* __restrict__ gub, float* __restrict__ dout)
{
  __shared__ float sact[ROWS * 1024];
  __shared__ float sscale[ROWS];
  __shared__ float sA[8], sB[8];

  const int b    = blockIdx.x;
  const int tid  = threadIdx.x;
  const int w    = tid >> 6;
  const int lane = tid & 63;
  int bi = 0;

  const float ropeInv = powf(10000.f, -(float)(lane & 31) * (1.f / 32.f));

  float4 wbuf[16];

  // ---------------- prep: hs[18][1024] ----------------
  if (b < 2) {
    const int c  = b * 512 + tid;
    const int st = step[0];
    const float tv = t_emb[(size_t)st * 1024 + c];
    hs[0 * 1024 + c] = dit_h[c] + tv;
    hs[9 * 1024 + c] = tv;
    #pragma unroll
    for (int p = 0; p < 4; p++) {
      hs[(1 + p)  * 1024 + c] = feat[(size_t)(p)     * 1024 + c];
      hs[(10 + p) * 1024 + c] = feat[(size_t)(4 + p) * 1024 + c];
    }
    #pragma unroll
    for (int p = 0; p < 4; p++) {
      float a = in_b[c];
      #pragma unroll
      for (int q4 = 0; q4 < 16; q4++) {
        float4 wv = *(const float4*)&in_w[(size_t)c * 64 + q4 * 4];
        float4 rv = *(const float4*)&random_[p * 64 + q4 * 4];
        a += dot4(wv, rv);
      }
      hs[(5 + p)  * 1024 + c] = a;
      hs[(14 + p) * 1024 + c] = a;
    }
  }

  // phase-static block mappings
  const int cbq = 12 * b;                   // QKV cols
  const int cg  = b & 63, ky = b >> 6;      // O / DOWN split
  const int cbo = 16 * cg;
  const int cbg = 16 * b;                   // GU cols
  const int cbd = 16 * cg;

  // helpers
  auto stage = [&](const float* src, int stride, int koff) {
    #pragma unroll
    for (int t = 0; t < 9; t++) {
      const int t4 = t * 512 + tid;
      const int r  = t4 >> 8;
      const int k4 = (t4 & 255) * 4;
      *(float4*)&sact[r * 1024 + k4] = *(const float4*)&src[(size_t)r * stride + koff + k4];
    }
  };

  // prefetch QKV layer-0 weights (waves 0-5, 2 cols x 4 chunks)
  {
    const float* qw = qkv_w;
    if (w < 6) {
      #pragma unroll
      for (int c = 0; c < 2; c++)
        #pragma unroll
        for (int ch = 0; ch < 4; ch++)
          wbuf[c * 4 + ch] = *(const float4*)&qw[(size_t)(cbq + 2 * w + c) * 1024 + ch * 256 + 4 * lane];
    }
  }
  gbar(&bars[(bi++) * 16]);

  for (int l = 0; l < 8; l++) {
    const float* qb = qkv_b + (size_t)l * 3072;
    const float* ow = o_w   + (size_t)l * 1024 * 1024;
    const float* gw = gu_w  + (size_t)l * 8192 * 1024;
    const float* dw = dn_w  + (size_t)l * 1024 * 4096;

    // ============ QKV: qkvb = rms(hs) @ qw^T + qb ============
    {
      stage(hs, 1024, 0);
      __syncthreads();
      if (w >= 6) {                 // waves 6,7: rms of 9 rows each
        #pragma unroll
        for (int t = 0; t < 9; t++) {
          const int r = (w - 6) * 9 + t;
          float ss = 0.f;
          #pragma unroll
          for (int q = 0; q < 4; q++) {
            float4 a = *(const float4*)&sact[r * 1024 + q * 256 + 4 * lane];
            ss += dot4(a, a);
          }
          ss = wred(ss);
          if (lane == 0) sscale[r] = rsqrtf(ss);
        }
      }
      float acc[2][ROWS];
      if (w < 6) {
        #pragma unroll
        for (int c = 0; c < 2; c++)
          #pragma unroll
          for (int r = 0; r < ROWS; r++) acc[c][r] = 0.f;
        #pragma unroll
        for (int ch = 0; ch < 4; ch++)
          #pragma unroll
          for (int r = 0; r < ROWS; r++) {
            float4 a = *(const float4*)&sact[r * 1024 + ch * 256 + 4 * lane];
            fma4(acc[0][r], wbuf[ch], a);
            fma4(acc[1][r], wbuf[4 + ch], a);
          }
      }
      __syncthreads();              // sscale ready
      if (w < 6) {
        #pragma unroll
        for (int c = 0; c < 2; c++)
          #pragma unroll
          for (int r = 0; r < ROWS; r++) {
            float v = wred(acc[c][r]);
            if (lane == 0) {
              const int col = cbq + 2 * w + c;
              qkvb[r * 3072 + col] = v * sscale[r] + qb[col];
            }
          }
      }
    }
    // prefetch O weights (2 cols x 1 chunk of K=256 slice)
    #pragma unroll
    for (int c = 0; c < 2; c++)
      wbuf[c] = *(const float4*)&ow[(size_t)(cbo + 2 * w + c) * 1024 + ky * 256 + 4 * lane];
    gbar(&bars[(bi++) * 16]);

    // ============ attn (4 heads, in-block) + O K-split, atomic += hs ============
    {
      // wave w: batch bb = w>>2, head slot hw = w&3, head h = 4*ky+hw
      const int bb = w >> 2, hw = w & 3, h = 4 * ky + hw;
      float q[9], k[9], v[9];
      #pragma unroll
      for (int i = 0; i < 9; i++) {
        const float* base = qkvb + (size_t)(bb * 9 + i) * 3072;
        q[i] = base[h * 64 + lane];
        k[i] = base[1024 + h * 64 + lane];
        v[i] = base[2048 + h * 64 + lane];
      }
      #pragma unroll
      for (int i = 0; i < 9; i++) {
        const float ang = (float)i * ropeInv;
        float sn, cs;
        __sincosf(ang, &sn, &cs);
        const float sgn = (lane < 32) ? -sn : sn;
        const float rq = __shfl_xor(q[i], 32);
        const float rk = __shfl_xor(k[i], 32);
        q[i] = q[i] * cs + rq * sgn;
        k[i] = k[i] * cs + rk * sgn;
      }
      #pragma unroll
      for (int i = 0; i < 9; i++) {
        float sc[9];
        #pragma unroll
        for (int jj = 0; jj < 9; jj++) sc[jj] = wred(q[i] * k[jj]);
        float mx = sc[0];
        #pragma unroll
        for (int jj = 1; jj < 9; jj++) mx = fmaxf(mx, sc[jj]);
        float den = 0.f;
        #pragma unroll
        for (int jj = 0; jj < 9; jj++) { sc[jj] = __expf(sc[jj] - mx); den += sc[jj]; }
        float o = 0.f;
        #pragma unroll
        for (int jj = 0; jj < 9; jj++) o += sc[jj] * v[jj];
        sact[(bb * 9 + i) * 256 + hw * 64 + lane] = o / den;
      }
      __syncthreads();
      float acc[2][ROWS];
      #pragma unroll
      for (int c = 0; c < 2; c++)
        #pragma unroll
        for (int r = 0; r < ROWS; r++) acc[c][r] = 0.f;
      #pragma unroll
      for (int r = 0; r < ROWS; r++) {
        float4 a = *(const float4*)&sact[r * 256 + 4 * lane];
        fma4(acc[0][r], wbuf[0], a);
        fma4(acc[1][r], wbuf[1], a);
      }
      #pragma unroll
      for (int c = 0; c < 2; c++)
        #pragma unroll
        for (int r = 0; r < ROWS; r++) {
          float v2 = wred(acc[c][r]);
          if (lane == 0) atomicAdd(&hs[r * 1024 + cbo + 2 * w + c], v2);
        }
    }
    // prefetch GU weights: rows {c0, c1, 4096+c0, 4096+c1} x 4 chunks
    {
      const int c0 = cbg + 2 * w;
      #pragma unroll
      for (int j = 0; j < 2; j++)
        #pragma unroll
        for (int ch = 0; ch < 4; ch++) {
          wbuf[j * 4 + ch]     = *(const float4*)&gw[(size_t)(c0 + j) * 1024 + ch * 256 + 4 * lane];
          wbuf[8 + j * 4 + ch] = *(const float4*)&gw[(size_t)(4096 + c0 + j) * 1024 + ch * 256 + 4 * lane];
        }
    }
    gbar(&bars[(bi++) * 16]);

    // ============ gate_up + silu -> gub ============
    {
      stage(hs, 1024, 0);
      __syncthreads();
      #pragma unroll
      for (int t = 0; t < 3; t++) {
        const int r = w + 8 * t;
        if (r < ROWS) {
          float ss = 0.f;
          #pragma unroll
          for (int q = 0; q < 4; q++) {
            float4 a = *(const float4*)&sact[r * 1024 + q * 256 + 4 * lane];
            ss += dot4(a, a);
          }
          ss = wred(ss);
          if (lane == 0) sscale[r] = rsqrtf(ss);
        }
      }
      __syncthreads();
      float acc[4][ROWS];
      #pragma unroll
      for (int j = 0; j < 4; j++)
        #pragma unroll
        for (int r = 0; r < ROWS; r++) acc[j][r] = 0.f;
      #pragma unroll
      for (int ch = 0; ch < 4; ch++)
        #pragma unroll
        for (int r = 0; r < ROWS; r++) {
          float4 a = *(const float4*)&sact[r * 1024 + ch * 256 + 4 * lane];
          fma4(acc[0][r], wbuf[ch], a);
          fma4(acc[1][r], wbuf[4 + ch], a);
          fma4(acc[2][r], wbuf[8 + ch], a);
          fma4(acc[3][r], wbuf[12 + ch], a);
        }
      const int c0 = cbg + 2 * w;
      #pragma unroll
      for (int r = 0; r < ROWS; r++) {
        float g0 = wred(acc[0][r]);
        float g1 = wred(acc[1][r]);
        float u0 = wred(acc[2][r]);
        float u1 = wred(acc[3][r]);
        if (lane == 0) {
          const float s = sscale[r];
          g0 *= s; g1 *= s; u0 *= s; u1 *= s;
          gub[r * 4096 + c0]     = g0 / (1.f + __expf(-g0)) * u0;
          gub[r * 4096 + c0 + 1] = g1 / (1.f + __expf(-g1)) * u1;
        }
      }
    }
    // prefetch DOWN weights: 2 cols x 4 chunks of K=1024 slice
    #pragma unroll
    for (int c = 0; c < 2; c++)
      #pragma unroll
      for (int ch = 0; ch < 4; ch++)
        wbuf[c * 4 + ch] = *(const float4*)&dw[(size_t)(cbd + 2 * w + c) * 4096 + ky * 1024 + ch * 256 + 4 * lane];
    gbar(&bars[(bi++) * 16]);

    // ============ down K-split, atomic += hs ============
    {
      stage(gub, 4096, ky * 1024);
      __syncthreads();
      float acc[2][ROWS];
      #pragma unroll
      for (int c = 0; c < 2; c++)
        #pragma unroll
        for (int r = 0; r < ROWS; r++) acc[c][r] = 0.f;
      #pragma unroll
      for (int ch = 0; ch < 4; ch++)
        #pragma unroll
        for (int r = 0; r < ROWS; r++) {
          float4 a = *(const float4*)&sact[r * 1024 + ch * 256 + 4 * lane];
          fma4(acc[0][r], wbuf[ch], a);
          fma4(acc[1][r], wbuf[4 + ch], a);
        }
      #pragma unroll
      for (int c = 0; c < 2; c++)
        #pragma unroll
        for (int r = 0; r < ROWS; r++) {
          float v2 = wred(acc[c][r]);
          if (lane == 0) atomicAdd(&hs[r * 1024 + cbd + 2 * w + c], v2);
        }
    }
    // prefetch next layer's QKV weights
    if (l < 7) {
      const float* qwn = qkv_w + (size_t)(l + 1) * 3072 * 1024;
      if (w < 6) {
        #pragma unroll
        for (int c = 0; c < 2; c++)
          #pragma unroll
          for (int ch = 0; ch < 4; ch++)
            wbuf[c * 4 + ch] = *(const float4*)&qwn[(size_t)(cbq + 2 * w + c) * 1024 + ch * 256 + 4 * lane];
      }
    }
    gbar(&bars[(bi++) * 16]);
  }

  // ============ out_proj + CFG combine (block 0) ============
  if (b == 0) {
    for (int t4 = tid; t4 < 2048; t4 += 512) {
      const int r8 = t4 / 256;
      const int k4 = (t4 % 256) * 4;
      const int row = (r8 >> 2) * 9 + 5 + (r8 & 3);
      *(float4*)&sact[r8 * 1024 + k4] = *(const float4*)&hs[(size_t)row * 1024 + k4];
    }
    __syncthreads();
    {
      float ss = 0.f;
      #pragma unroll
      for (int qq = 0; qq < 4; qq++) {
        float4 a = *(const float4*)&sact[w * 1024 + 4 * lane + 256 * qq];
        ss += dot4(a, a);
      }
      ss = wred(ss);
      if (lane == 0) sA[w] = rsqrtf(ss);
    }
    __syncthreads();
    // 512 threads: (r8, c) = (tid&7, tid>>3)
    float outv[1];
    {
      const int r8 = tid & 7;
      const int c  = tid >> 3;
      float a0 = 0.f, a1 = 0.f;
      #pragma unroll 4
      for (int k4 = 0; k4 < 128; k4++) {
        a0 += dot4(*(const float4*)&sact[r8 * 1024 + 8 * k4],
                   *(const float4*)&op_w[(size_t)c * 1024 + 8 * k4]);
        a1 += dot4(*(const float4*)&sact[r8 * 1024 + 8 * k4 + 4],
                   *(const float4*)&op_w[(size_t)c * 1024 + 8 * k4 + 4]);
      }
      outv[0] = (a0 + a1) * sA[r8] + op_b[c];
    }
    __syncthreads();
    {
      const int r8 = tid & 7;
      const int c  = tid >> 3;
      sact[r8 * 64 + c] = outv[0];   // sout[r8][c] in first 512 floats
    }
    __syncthreads();
    float pos = 0.f, neg = 0.f, dd = 0.f, sq = 0.f;
    if (tid < 256) {
      pos = sact[tid]; neg = sact[256 + tid];
      dd = pos * neg; sq = neg * neg;
    }
    dd = wred(dd); sq = wred(sq);
    if (lane == 0) { sA[w] = dd; sB[w] = sq; }
    __syncthreads();
    if (tid < 256) {
      float dot = 0.f, sqs = 0.f;
      #pragma unroll
      for (int jj = 0; jj < 8; jj++) { dot += sA[jj]; sqs += sB[jj]; }
      const float guided = cfg[0] * pos + cfgm[0] * (dot / sqs) * neg;
      dout[tid] = random_[tid] + guided * dt[step[0]];
    }
  }
}

extern "C" void kernel_launch(void* const* d_in, const int* in_sizes, int n_in,
                              void* d_out, int out_size, void* d_ws, size_t ws_size,
                              hipStream_t stream)
{
  const int*   step    = (const int*)  d_in[0];
  const float* random_ = (const float*)d_in[1];
  const float* dit_h   = (const float*)d_in[2];
  const float* feat    = (const float*)d_in[3];
  const float* cfg     = (const float*)d_in[4];
  const float* cfgm    = (const float*)d_in[5];
  const float* t_emb   = (const float*)d_in[6];
  const float* dt      = (const float*)d_in[7];
  const float* in_w    = (const float*)d_in[8];
  const float* in_b    = (const float*)d_in[9];
  const float* qkv_w   = (const float*)d_in[10];
  const float* qkv_b   = (const float*)d_in[11];
  const float* o_w     = (const float*)d_in[12];
  const float* gu_w    = (const float*)d_in[13];
  const float* dn_w    = (const float*)d_in[14];
  const float* op_w    = (const float*)d_in[15];
  const float* op_b    = (const float*)d_in[16];

  unsigned* bars = (unsigned*)d_ws;                       // [0, 4096)
  float* hs   = (float*)((char*)d_ws + 4096);             // 18*1024
  float* qkvb = hs + ROWS * 1024;                         // 18*3072
  float* gub  = qkvb + ROWS * 3072;                       // 18*4096
  float* dout = (float*)d_out;

  hipMemsetAsync(d_ws, 0, 4096, stream);

  void* args[] = {
    (void*)&step, (void*)&random_, (void*)&dit_h, (void*)&feat, (void*)&cfg,
    (void*)&cfgm, (void*)&t_emb, (void*)&dt, (void*)&in_w, (void*)&in_b,
    (void*)&qkv_w, (void*)&qkv_b, (void*)&o_w, (void*)&gu_w, (void*)&dn_w,
    (void*)&op_w, (void*)&op_b, (void*)&bars,
    (void*)&hs, (void*)&qkvb, (void*)&gub, (void*)&dout
  };
  hipLaunchCooperativeKernel((void*)vox_persist, dim3(NBLK), dim3(512),
                             args, 0, stream);
}